// Round 12
// baseline (44.230 us; speedup 1.0000x reference)
//
#include <hip/hip_runtime.h>

// Problem constants (B=8, C=128, H=W=48 -> N=2304)
#define NTOK 2304
#define CC   128

typedef __attribute__((ext_vector_type(8))) short bf16x8;
typedef __attribute__((ext_vector_type(4))) float f32x4;

// round-to-nearest-even fp32 -> bf16
__device__ __forceinline__ unsigned f2bf(float f) {
  unsigned u = __builtin_bit_cast(unsigned, f);
  u += 0x7FFFu + ((u >> 16) & 1u);
  return (u >> 16) & 0xFFFFu;
}
__device__ __forceinline__ unsigned pk2(float a, float b) {
  return f2bf(a) | (f2bf(b) << 16);
}

// async global->LDS, 16B per lane; LDS dest = wave-uniform base + lane*16,
// global src per-lane (guide §5 / m97; size must be literal 16)
__device__ __forceinline__ void g2l16(const void* g, void* l) {
  __builtin_amdgcn_global_load_lds(
      (const __attribute__((address_space(1))) unsigned int*)g,
      (__attribute__((address_space(3))) unsigned int*)l, 16, 0, 0);
}

// Prep (validated R8-R11): ONE pass over x,y. Computes exact fp32 norms
// (sx from x, sy from y; reference quirk: P[i][j] = ||x_i||^2 + ||y_j||^2
// - 2*y_i.x_j) AND writes a bf16 "LDS image": img[b][n] = 256 B row of
// K-contiguous bf16 with slot swizzle slot=(k>>3)^(n&15)^((n>>4)&3)
// pre-applied (gemm reads recompute the ABSOLUTE-n XOR terms, so any
// 16-aligned tile base works).
__global__ __launch_bounds__(256) void pwd_prep(
    const float* __restrict__ x, const float* __restrict__ y,
    char* __restrict__ imgX, char* __restrict__ imgY,
    float* __restrict__ sx, float* __restrict__ sy) {
  __shared__ float part[4][64];
  const int tid = threadIdx.x;
  const int nl  = tid & 63;
  const int cq  = tid >> 6;            // k-quarter: 32 k's = 4 octets
  const int n   = blockIdx.x * 64 + nl;
  const int b   = blockIdx.y;
  const int sel = blockIdx.z;
  const float* src = sel ? y : x;
  char* img = sel ? imgY : imgX;

  const float* p = src + ((size_t)b * CC + cq * 32) * NTOK + n;
  float v[32];
#pragma unroll
  for (int k = 0; k < 32; ++k) v[k] = p[(size_t)k * NTOK];

  float s = 0.f;
#pragma unroll
  for (int k = 0; k < 32; ++k) s = fmaf(v[k], v[k], s);
  part[cq][nl] = s;

  char* row = img + ((size_t)b * NTOK + n) * 256;
  const int swz = (n & 15) ^ ((n >> 4) & 3);
#pragma unroll
  for (int oo = 0; oo < 4; ++oo) {
    const int o = cq * 4 + oo;         // k-octet 0..15
    uint4 wv;
    wv.x = pk2(v[oo * 8 + 0], v[oo * 8 + 1]);
    wv.y = pk2(v[oo * 8 + 2], v[oo * 8 + 3]);
    wv.z = pk2(v[oo * 8 + 4], v[oo * 8 + 5]);
    wv.w = pk2(v[oo * 8 + 6], v[oo * 8 + 7]);
    *(uint4*)(row + ((o ^ swz) * 16)) = wv;
  }
  __syncthreads();
  if (tid < 64) {
    float t = part[0][tid] + part[1][tid] + part[2][tid] + part[3][tid];
    (sel ? sy : sx)[b * NTOK + blockIdx.x * 64 + tid] = t;
  }
}

// Main GEMM: 32i x 128j tile -> epilogue store runs of 512 B (vs R11's 256 B;
// testing "longer contiguous runs -> higher HBM write efficiency", the
// confirmed R11 lever at double strength).
//   D[m=j][n=i] = sum_k x[k][j]*y[k][i]  (= y_i . x_j)
// 256 threads / 4 waves; wave w owns j-band [32w,32w+32) x all 32 i.
// LDS 40KB -> 4 blocks/CU. Staging = 10x global_load_lds dwordx4/thread.
__global__ __launch_bounds__(256, 4) void pwd_gemm(
    const char* __restrict__ imgX, const char* __restrict__ imgY,
    const float* __restrict__ sx, const float* __restrict__ sy,
    float* __restrict__ out) {
  __shared__ __attribute__((aligned(16))) char smem[40960];
  char* const smX = smem;            // x panel: 128 j-rows * 256 B
  char* const smY = smem + 32768;    // y panel:  32 i-rows * 256 B

  const int tid = threadIdx.x;

  // XCD swizzle: grid 10368 = 8*1296; bid%8 = batch (one batch per XCD L2).
  const int bid = blockIdx.x;
  const int b   = bid & 7;
  const int rem = bid >> 3;            // 0..1295
  const int byy = rem / 18;            // 0..71
  const int bxx = rem - byy * 18;      // 0..17
  const int i0 = byy * 32;             // output rows (i), 32-aligned
  const int j0 = bxx * 128;            // output cols (j), 128-aligned

  const int w  = tid >> 6;             // wave 0..3
  const int l  = tid & 63;
  const int lr = l & 15;
  const int lg = l >> 4;
  const int wj = w * 32;               // wave j band

  // y-panel swizzle correction: i0 is only 32-aligned, so the image's
  // (n>>4)&3 term differs from tile-local by iswz = (i0>>4)&3 (no carry:
  // i0%16==0, n<32).
  const int iswz = (i0 >> 4) & 3;

  // ---------------- stage panels via async DMA ------------------------------
  {
    const char* gx = imgX + ((size_t)b * NTOK + j0) * 256;   // 32 KB
    const char* gy = imgY + ((size_t)b * NTOK + i0) * 256;   //  8 KB
    const int o0 = tid * 16;
#pragma unroll
    for (int it = 0; it < 8; ++it)
      g2l16(gx + o0 + it * 4096, smX + o0 + it * 4096);
#pragma unroll
    for (int it = 0; it < 2; ++it)
      g2l16(gy + o0 + it * 4096, smY + o0 + it * 4096);
  }

  // ---------------- hoist norms into registers (in flight over DMA) ---------
  float sxr[2];
#pragma unroll
  for (int nf = 0; nf < 2; ++nf)                 // x norm at row i
    sxr[nf] = sx[b * NTOK + i0 + nf * 16 + lr];
  f32x4 syq[2];
#pragma unroll
  for (int mf = 0; mf < 2; ++mf)                 // y norms at j quad
    syq[mf] = *(const f32x4*)(sy + b * NTOK + j0 + wj + mf * 16 + lg * 4);

  __syncthreads();   // drains vmcnt (DMA complete)

  // ---------------- compute: wave tile 32j x 32i ----------------------------
  f32x4 acc[2][2] = {};
#pragma unroll
  for (int ks = 0; ks < 4; ++ks) {
    const int o = ks * 4 + lg;           // 16B slot (8 k's)
    bf16x8 ax[2], by[2];
#pragma unroll
    for (int mf = 0; mf < 2; ++mf) {     // A-frag rows = j (j0 128-aligned)
      const int n = wj + mf * 16 + lr;
      const int slot = o ^ (n & 15) ^ ((n >> 4) & 3);
      ax[mf] = *(const bf16x8*)(smX + n * 256 + slot * 16);
    }
#pragma unroll
    for (int nf = 0; nf < 2; ++nf) {     // B-frag rows = i (absolute swizzle)
      const int n = nf * 16 + lr;
      const int slot = o ^ (n & 15) ^ (((n >> 4) + iswz) & 3);
      by[nf] = *(const bf16x8*)(smY + n * 256 + slot * 16);
    }
#pragma unroll
    for (int mf = 0; mf < 2; ++mf)
#pragma unroll
      for (int nf = 0; nf < 2; ++nf)
        acc[mf][nf] = __builtin_amdgcn_mfma_f32_16x16x32_bf16(
            ax[mf], by[nf], acc[mf][nf], 0, 0, 0);
  }

  // ---------------- epilogue: LDS bounce -> contiguous 512B-run stores ------
  // tile[32][128] fp32 (16 KB), 16B chunks: addr = row*512 + ((c32 ^
  // (row&15))*16). Write instr (fixed mf,nf): s mod 8 uniform -> free.
  // Read instr: 2 rows x 32 distinct slots -> 2-way -> free.
  {
    float* const tile = (float*)smem;    // panels dead after compute
    __syncthreads();
#pragma unroll
    for (int mf = 0; mf < 2; ++mf)
#pragma unroll
      for (int nf = 0; nf < 2; ++nf) {
        f32x4 vv;
#pragma unroll
        for (int r = 0; r < 4; ++r)
          vv[r] = sxr[nf] + syq[mf][r] - 2.0f * acc[mf][nf][r];
        const int row = nf * 16 + lr;        // local i
        const int c32 = (wj >> 2) + mf * 4 + lg;  // 16B chunk (local j/4)
        *(f32x4*)((char*)tile + row * 512 + ((c32 ^ (row & 15)) * 16)) = vv;
      }
    __syncthreads();
    // stream out: instr = 64 consecutive chunks = 2 rows x 512 B contig
#pragma unroll
    for (int it = 0; it < 4; ++it) {
      const int c   = it * 256 + tid;    // chunk id 0..1023
      const int row = c >> 5;
      const int c32 = c & 31;
      f32x4 vv = *(const f32x4*)((char*)tile + row * 512 +
                                 ((c32 ^ (row & 15)) * 16));
      *(f32x4*)(out + ((size_t)b * NTOK + i0 + row) * NTOK + j0 + c32 * 4) = vv;
    }
  }
}

extern "C" void kernel_launch(void* const* d_in, const int* in_sizes, int n_in,
                              void* d_out, int out_size, void* d_ws, size_t ws_size,
                              hipStream_t stream) {
  (void)in_sizes; (void)n_in; (void)out_size; (void)ws_size;
  const float* x = (const float*)d_in[0];
  const float* y = (const float*)d_in[1];
  float* out = (float*)d_out;

  // workspace layout: bf16 images (2 x 4.72 MB) + norms (2 x 73.7 KB)
  char* imgX = (char*)d_ws;
  char* imgY = imgX + (size_t)8 * NTOK * 256;
  float* sx  = (float*)(imgY + (size_t)8 * NTOK * 256);
  float* sy  = sx + 8 * NTOK;

  dim3 gp(NTOK / 64, 8, 2);
  pwd_prep<<<gp, dim3(256), 0, stream>>>(x, y, imgX, imgY, sx, sy);

  dim3 gg(72 * 18 * 8);                  // one 32x128 tile per block
  pwd_gemm<<<gg, dim3(256), 0, stream>>>(imgX, imgY, sx, sy, out);
}

// Round 13
// 42.891 us; speedup vs baseline: 1.0312x; 1.0312x over previous
//
#include <hip/hip_runtime.h>

// Problem constants (B=8, C=128, H=W=48 -> N=2304)
#define NTOK 2304
#define CC   128

typedef __attribute__((ext_vector_type(8))) short bf16x8;
typedef __attribute__((ext_vector_type(4))) float f32x4;

// round-to-nearest-even fp32 -> bf16
__device__ __forceinline__ unsigned f2bf(float f) {
  unsigned u = __builtin_bit_cast(unsigned, f);
  u += 0x7FFFu + ((u >> 16) & 1u);
  return (u >> 16) & 0xFFFFu;
}
__device__ __forceinline__ unsigned pk2(float a, float b) {
  return f2bf(a) | (f2bf(b) << 16);
}

// async global->LDS, 16B per lane; LDS dest = wave-uniform base + lane*16,
// global src per-lane (guide §5 / m97; size must be literal 16)
__device__ __forceinline__ void g2l16(const void* g, void* l) {
  __builtin_amdgcn_global_load_lds(
      (const __attribute__((address_space(1))) unsigned int*)g,
      (__attribute__((address_space(3))) unsigned int*)l, 16, 0, 0);
}

// Prep, 2x parallelism vs R11 (1152 blocks = 4.5/CU, 16-deep load chain vs
// 32): ONE pass over x,y; exact fp32 norms (sx from x, sy from y; reference
// quirk: P[i][j] = ||x_i||^2 + ||y_j||^2 - 2*y_i.x_j) AND bf16 "LDS image":
// img[b][n] = 256 B row of K-contiguous bf16, slot swizzle
// slot=(k>>3)^(n&15)^((n>>4)&3) pre-applied.
__global__ __launch_bounds__(256) void pwd_prep(
    const float* __restrict__ x, const float* __restrict__ y,
    char* __restrict__ imgX, char* __restrict__ imgY,
    float* __restrict__ sx, float* __restrict__ sy) {
  __shared__ float part[8][32];
  const int tid = threadIdx.x;
  const int nl  = tid & 31;            // token within 32-chunk
  const int cg  = tid >> 5;            // k-group 0..7 (16 k's = 2 octets)
  const int n   = blockIdx.x * 32 + nl;
  const int b   = blockIdx.y;
  const int sel = blockIdx.z;
  const float* src = sel ? y : x;
  char* img = sel ? imgY : imgX;

  const float* p = src + ((size_t)b * CC + cg * 16) * NTOK + n;
  float v[16];
#pragma unroll
  for (int k = 0; k < 16; ++k) v[k] = p[(size_t)k * NTOK];

  float s = 0.f;
#pragma unroll
  for (int k = 0; k < 16; ++k) s = fmaf(v[k], v[k], s);
  part[cg][nl] = s;

  char* row = img + ((size_t)b * NTOK + n) * 256;
  const int swz = (n & 15) ^ ((n >> 4) & 3);
#pragma unroll
  for (int oo = 0; oo < 2; ++oo) {
    const int o = cg * 2 + oo;         // k-octet 0..15
    uint4 wv;
    wv.x = pk2(v[oo * 8 + 0], v[oo * 8 + 1]);
    wv.y = pk2(v[oo * 8 + 2], v[oo * 8 + 3]);
    wv.z = pk2(v[oo * 8 + 4], v[oo * 8 + 5]);
    wv.w = pk2(v[oo * 8 + 6], v[oo * 8 + 7]);
    *(uint4*)(row + ((o ^ swz) * 16)) = wv;
  }
  __syncthreads();
  if (tid < 32) {
    float t = 0.f;
#pragma unroll
    for (int g = 0; g < 8; ++g) t += part[g][tid];
    (sel ? sy : sx)[b * NTOK + blockIdx.x * 32 + tid] = t;
  }
}

// Main GEMM (R11 config, best measured): 64x64 tile, 256 thr / 4 waves,
// LDS 32KB -> 5 blocks/CU. Epilogue via LDS bounce -> 4x256B-run stores,
// now NONTEMPORAL (A/B at the 256B-run operating point; R10's NT-null was
// at 64B granules where granularity masked cache policy).
//   D[m=j][n=i] = sum_k x[k][j]*y[k][i]  (= y_i . x_j)
__global__ __launch_bounds__(256, 5) void pwd_gemm(
    const char* __restrict__ imgX, const char* __restrict__ imgY,
    const float* __restrict__ sx, const float* __restrict__ sy,
    float* __restrict__ out) {
  __shared__ __attribute__((aligned(16))) char smem[32768];
  char* const smX = smem;            // x panel: 64 j-rows * 256 B
  char* const smY = smem + 16384;    // y panel: 64 i-rows * 256 B

  const int tid = threadIdx.x;

  // XCD swizzle: grid 10368 = 8*1296; bid%8 = batch (one batch per XCD L2).
  const int bid = blockIdx.x;
  const int b   = bid & 7;
  const int rem = bid >> 3;            // 0..1295
  const int byy = rem / 36;
  const int bxx = rem - byy * 36;
  const int i0 = byy * 64;             // output rows (i)
  const int j0 = bxx * 64;             // output cols (j)

  const int w  = tid >> 6;             // wave 0..3
  const int l  = tid & 63;
  const int lr = l & 15;
  const int lg = l >> 4;
  const int wi = w * 16;               // wave i band

  // ---------------- stage panels via async DMA ------------------------------
  // wave w copies 4KB chunk w of each 16KB panel (4 x 1KB instructions).
  {
    const char* gx = imgX + ((size_t)b * NTOK + j0) * 256;
    const char* gy = imgY + ((size_t)b * NTOK + i0) * 256;
    const int wb = w * 4096;
    const size_t o0 = (size_t)wb + (size_t)l * 16;
#pragma unroll
    for (int it = 0; it < 4; ++it)
      g2l16(gx + o0 + it * 1024, smX + wb + it * 1024);
#pragma unroll
    for (int it = 0; it < 4; ++it)
      g2l16(gy + o0 + it * 1024, smY + wb + it * 1024);
  }

  // ---------------- hoist norms into registers (in flight over DMA) ---------
  const float sxr = sx[b * NTOK + i0 + wi + lr];        // x norm at row i
  f32x4 syq[4];
#pragma unroll
  for (int mf = 0; mf < 4; ++mf)                         // y norms at j quad
    syq[mf] = *(const f32x4*)(sy + b * NTOK + j0 + mf * 16 + lg * 4);

  __syncthreads();   // drains vmcnt (DMA complete)

  // ---------------- compute: wave tile 64j x 16i ----------------------------
  f32x4 acc[4] = {};
#pragma unroll
  for (int ks = 0; ks < 4; ++ks) {
    const int o = ks * 4 + lg;           // 16B slot (8 k's)
    bf16x8 ax[4], by;
#pragma unroll
    for (int mf = 0; mf < 4; ++mf) {     // A-frag rows = j
      const int n = mf * 16 + lr;
      const int slot = o ^ (n & 15) ^ ((n >> 4) & 3);
      ax[mf] = *(const bf16x8*)(smX + n * 256 + slot * 16);
    }
    {                                    // B-frag rows = i
      const int n = wi + lr;
      const int slot = o ^ (n & 15) ^ ((n >> 4) & 3);
      by = *(const bf16x8*)(smY + n * 256 + slot * 16);
    }
#pragma unroll
    for (int mf = 0; mf < 4; ++mf)
      acc[mf] = __builtin_amdgcn_mfma_f32_16x16x32_bf16(ax[mf], by, acc[mf],
                                                        0, 0, 0);
  }

  // ---------------- epilogue: LDS bounce -> 256B-run NT stores --------------
  // tile[64][64] fp32 (16 KB), 16B chunks XOR-swizzled: chunk addr =
  // row*256 + ((c16 ^ (row&15))*16). Both bounce write and read are <=2-way
  // bank aliased (free).
  {
    float* const tile = (float*)smem;    // panels dead after compute
    __syncthreads();
#pragma unroll
    for (int mf = 0; mf < 4; ++mf) {
      f32x4 vv;
#pragma unroll
      for (int r = 0; r < 4; ++r)
        vv[r] = sxr + syq[mf][r] - 2.0f * acc[mf][r];
      const int row = wi + lr;           // local i
      const int c16 = mf * 4 + lg;       // 16B chunk within row (local j/4)
      *(f32x4*)((char*)tile + row * 256 + ((c16 ^ (row & 15)) * 16)) = vv;
    }
    __syncthreads();
    // stream out: instr = 64 consecutive 16B chunks = 4 rows x 256 B contig
#pragma unroll
    for (int it = 0; it < 4; ++it) {
      const int c   = it * 256 + tid;    // chunk id 0..1023
      const int row = c >> 4;
      const int c16 = c & 15;
      f32x4 vv = *(const f32x4*)((char*)tile + row * 256 +
                                 ((c16 ^ (row & 15)) * 16));
      __builtin_nontemporal_store(
          vv, (f32x4*)(out + ((size_t)b * NTOK + i0 + row) * NTOK + j0 + c16 * 4));
    }
  }
}

extern "C" void kernel_launch(void* const* d_in, const int* in_sizes, int n_in,
                              void* d_out, int out_size, void* d_ws, size_t ws_size,
                              hipStream_t stream) {
  (void)in_sizes; (void)n_in; (void)out_size; (void)ws_size;
  const float* x = (const float*)d_in[0];
  const float* y = (const float*)d_in[1];
  float* out = (float*)d_out;

  // workspace layout: bf16 images (2 x 4.72 MB) + norms (2 x 73.7 KB)
  char* imgX = (char*)d_ws;
  char* imgY = imgX + (size_t)8 * NTOK * 256;
  float* sx  = (float*)(imgY + (size_t)8 * NTOK * 256);
  float* sy  = sx + 8 * NTOK;

  dim3 gp(NTOK / 32, 8, 2);              // 1152 blocks (2x R11's prep)
  pwd_prep<<<gp, dim3(256), 0, stream>>>(x, y, imgX, imgY, sx, sy);

  dim3 gg(36 * 36 * 8);                  // one 64x64 tile per block
  pwd_gemm<<<gg, dim3(256), 0, stream>>>(imgX, imgY, sx, sy, out);
}